// Round 4
// baseline (1274.983 us; speedup 1.0000x reference)
//
#include <hip/hip_runtime.h>

#define Dn 512
#define Bn 32
#define Tn 2048
#define BT 65536   // Bn*Tn

typedef unsigned short u16;
typedef __attribute__((ext_vector_type(8))) short short8;   // 8 bf16 = 4 VGPRs (MFMA A/B frag)
typedef __attribute__((ext_vector_type(4))) float floatx4;  // MFMA C/D frag

__device__ __forceinline__ u16 f2bf(float f) {
    unsigned u = __float_as_uint(f);
    unsigned r = (u + 0x7FFFu + ((u >> 16) & 1u)) >> 16;    // RNE
    return (u16)r;
}
__device__ __forceinline__ float bf2f(u16 s) { return __uint_as_float(((unsigned)s) << 16); }

// ---------------------------------------------------------------------------
// 1) x[b][t][d] (f32) -> Xt[d][b*Tn+t] (bf16), LDS 64x64 tile transpose.
// ---------------------------------------------------------------------------
__global__ __launch_bounds__(256) void k_transpose(const float* __restrict__ x,
                                                   u16* __restrict__ Xt) {
    int tt = blockIdx.x;   // t-tile 0..31
    int dt = blockIdx.y;   // d-tile 0..7
    int b  = blockIdx.z;   // 0..31
    __shared__ u16 sT[64][68];  // [d][t], padded
    int tid = threadIdx.x;
    int row = tid >> 4;            // 0..15 (t)
    int c4  = (tid & 15) * 4;      // 0..60 (d)
    const float* src = x + ((long)b * Tn + (long)tt * 64) * Dn + dt * 64;
#pragma unroll
    for (int q = 0; q < 4; q++) {
        int r = row + q * 16;
        floatx4 v = *(const floatx4*)(src + (long)r * Dn + c4);
        sT[c4 + 0][r] = f2bf(v[0]);
        sT[c4 + 1][r] = f2bf(v[1]);
        sT[c4 + 2][r] = f2bf(v[2]);
        sT[c4 + 3][r] = f2bf(v[3]);
    }
    __syncthreads();
    int drow = tid >> 3;           // 0..31 (d)
    int koff = (tid & 7) * 8;      // 0..56 (t)
    long kout = (long)b * Tn + (long)tt * 64 + koff;
#pragma unroll
    for (int p = 0; p < 2; p++) {
        int dr = drow + p * 32;
        u16 tmp[8];
#pragma unroll
        for (int j = 0; j < 8; j++) tmp[j] = sT[dr][koff + j];
        *(short8*)(Xt + (long)(dt * 64 + dr) * BT + kout) = *(short8*)tmp;
    }
}

// ---------------------------------------------------------------------------
// 2) mu[b][d] = (1/T) sum_t Xt[d][b*Tn+t]   (wave per (b,d))
// ---------------------------------------------------------------------------
__global__ __launch_bounds__(256) void k_mu(const u16* __restrict__ Xt,
                                            float* __restrict__ mu) {
    int tid = threadIdx.x;
    int wave = tid >> 6, lane = tid & 63;
    int p = blockIdx.x * 4 + wave;      // 0..16383 == b*512+d
    int b = p >> 9, d = p & 511;
    const u16* src = Xt + (long)d * BT + (long)b * Tn;
    float s = 0.f;
#pragma unroll
    for (int c = 0; c < 4; c++) {
        short8 v = *(const short8*)(src + c * 512 + lane * 8);
#pragma unroll
        for (int j = 0; j < 8; j++) s += bf2f((u16)v[j]);
    }
#pragma unroll
    for (int off = 32; off; off >>= 1) s += __shfl_down(s, off, 64);
    if (lane == 0) mu[p] = s * (1.0f / Tn);
}

// ---------------------------------------------------------------------------
// 3) Gram partials: partial[chunk][d][e] = sum_{k in chunk} Xt[d][k]*Xt[e][k]
//    bf16 MFMA 16x16x32, 128x128 tile, BK=32, 16 K-chunks x 10 sym positions.
// ---------------------------------------------------------------------------
#define LDK 40   // padded LDS row stride (bf16 elems) to spread banks
__global__ __launch_bounds__(256) void k_gram(const u16* __restrict__ Xt,
                                              float* __restrict__ partial) {
    int chunk = blockIdx.x;             // 0..15 (K-chunk of 4096)
    int pos = blockIdx.y;               // 0..9 upper-block-triangle positions
    int di = (pos < 4) ? 0 : (pos < 7) ? 1 : (pos < 9) ? 2 : 3;
    int start = di * 4 - (di * (di - 1)) / 2;   // 0,4,7,9
    int ei = di + (pos - start);
    int d0 = di * 128, e0 = ei * 128;

    __shared__ u16 sA[128 * LDK];
    __shared__ u16 sB[128 * LDK];
    int tid = threadIdx.x;
    int wave = tid >> 6, lane = tid & 63;
    int wm = wave & 1, wn = wave >> 1;  // 2x2 waves over 128x128
    int lrow = tid >> 2;                // 0..63
    int lk = (tid & 3) * 8;             // 0,8,16,24
    const u16* gA = Xt + (long)(d0 + lrow) * BT + (long)chunk * 4096 + lk;
    const u16* gB = Xt + (long)(e0 + lrow) * BT + (long)chunk * 4096 + lk;
    int m = lane & 15, g = lane >> 4;

    floatx4 acc[4][4] = {};
    for (int kk = 0; kk < 4096; kk += 32) {
        short8 a0 = *(const short8*)(gA + kk);
        short8 a1 = *(const short8*)(gA + 64l * BT + kk);
        short8 b0 = *(const short8*)(gB + kk);
        short8 b1 = *(const short8*)(gB + 64l * BT + kk);
        __syncthreads();   // previous iteration's LDS reads done
        *(short8*)(sA + lrow * LDK + lk) = a0;
        *(short8*)(sA + (lrow + 64) * LDK + lk) = a1;
        *(short8*)(sB + lrow * LDK + lk) = b0;
        *(short8*)(sB + (lrow + 64) * LDK + lk) = b1;
        __syncthreads();
        short8 af[4], bf[4];
#pragma unroll
        for (int i = 0; i < 4; i++)
            af[i] = *(const short8*)(sA + (wm * 64 + i * 16 + m) * LDK + g * 8);
#pragma unroll
        for (int j = 0; j < 4; j++)
            bf[j] = *(const short8*)(sB + (wn * 64 + j * 16 + m) * LDK + g * 8);
#pragma unroll
        for (int i = 0; i < 4; i++)
#pragma unroll
            for (int j = 0; j < 4; j++)
                acc[i][j] = __builtin_amdgcn_mfma_f32_16x16x32_bf16(af[i], bf[j], acc[i][j], 0, 0, 0);
    }
    // C/D layout: col = lane&15, row = (lane>>4)*4 + reg   [m89-verified]
    float* P = partial + (long)chunk * (512l * 512);
    int col = lane & 15, rowg = (lane >> 4) * 4;
#pragma unroll
    for (int i = 0; i < 4; i++)
#pragma unroll
        for (int j = 0; j < 4; j++) {
            int rr = d0 + wm * 64 + i * 16 + rowg;
            int cc = e0 + wn * 64 + j * 16 + col;
#pragma unroll
            for (int r = 0; r < 4; r++) P[(long)(rr + r) * 512 + cc] = acc[i][j][r];
        }
}

// ---------------------------------------------------------------------------
// 4) cov[d][e] = (G[d][e] - T * sum_b mu[b,d]*mu[b,e]) / ((T-1)*B)
// ---------------------------------------------------------------------------
__global__ __launch_bounds__(256) void k_assemble(const float* __restrict__ partial,
                                                  const float* __restrict__ mu,
                                                  float* __restrict__ A) {
    int d = blockIdx.y;
    int e = blockIdx.x * 256 + threadIdx.x;
    int bd = d >> 7, be = e >> 7;
    long idx = (bd <= be) ? ((long)d * 512 + e) : ((long)e * 512 + d);  // symmetric mirror
    float s = 0.f;
#pragma unroll
    for (int c = 0; c < 16; c++) s += partial[c * (512l * 512) + idx];
    float msum = 0.f;
#pragma unroll
    for (int b = 0; b < 32; b++) msum += mu[b * 512 + d] * mu[b * 512 + e];
    A[(long)d * 512 + e] = (s - (float)Tn * msum) * (1.0f / ((Tn - 1.0f) * Bn));
}

// ---------------------------------------------------------------------------
// 5a) Fused Cholesky panel (rounds 1-3 lesson: per-thread arrays indexed by
//     loop vars land in scratch, NOT VGPRs -> 150+us/wave. Everything here is
//     LDS-resident with rolled loops; zero per-thread arrays.)
//     Every block redundantly factors the 64x64 diag block in LDS
//     (column-major sD[c*68+r]: per-lane accesses consecutive across lanes ->
//     conflict-free; L11 element reads are wave-uniform broadcasts).
//     Block 0 writes the factored diag; blocks 1..nb forward-substitute one
//     64-row stripe of L21 (rows in LDS; solve loop needs NO barriers: each
//     lane reads only its own prior columns + uniform L11/invD).
// ---------------------------------------------------------------------------
__global__ __launch_bounds__(64) void k_chol_panel(float* __restrict__ A, int kb) {
    const int k0 = kb * 64;
    const int lane = threadIdx.x;       // 64 threads = 1 wave
    __shared__ float sD[64 * 68];       // diag, column-major: sD[c*68 + r]
    __shared__ float sS[64 * 68];       // stripe, column-major: sS[c*68 + r]
    __shared__ float sInv[64];

    // stage diag block column-major; row-sweep -> coalesced global reads
    {
        const float* Ad = A + (long)k0 * 512 + k0;
#pragma unroll 8
        for (int r = 0; r < 64; r++)
            sD[lane * 68 + r] = Ad[(long)r * 512 + lane];
    }
    __syncthreads();

    // factor 64x64 (right-looking rank-1), rolled loops
    for (int k = 0; k < 64; k++) {
        float akk = sD[k * 68 + k];                  // uniform broadcast
        float sd = sqrtf(akk);
        float inv = 1.0f / sd;
        float ark = sD[k * 68 + lane];               // (row=lane, col=k)
        float lik = (lane == k) ? sd : ark * inv;
        sD[k * 68 + lane] = lik;                     // rows<k write upper junk: never read
        __syncthreads();
        for (int j = k + 1; j < 64; j++) {
            float ljk = sD[k * 68 + j];              // uniform broadcast
            sD[j * 68 + lane] = fmaf(-lik, ljk, sD[j * 68 + lane]);
        }
        __syncthreads();
    }
    sInv[lane] = 1.0f / sD[lane * 68 + lane];
    __syncthreads();

    if (blockIdx.x == 0) {
        // write back factored diag (junk upper triangle is never read downstream)
        float* Ad = A + (long)k0 * 512 + k0;
#pragma unroll 8
        for (int r = 0; r < 64; r++)
            Ad[(long)r * 512 + lane] = sD[lane * 68 + r];
    } else {
        int rbase = k0 + 64 + (blockIdx.x - 1) * 64;
        const float* As = A + (long)rbase * 512 + k0;
#pragma unroll 8
        for (int r = 0; r < 64; r++)
            sS[lane * 68 + r] = As[(long)r * 512 + lane];
        __syncthreads();
        // forward substitution, row = lane; no barriers (own-row + uniform reads only)
        for (int c = 0; c < 64; c++) {
            float val = sS[c * 68 + lane];
            float s0 = 0.f, s1 = 0.f;
            int m = 0;
            for (; m + 1 < c; m += 2) {
                s0 = fmaf(sS[m * 68 + lane], sD[m * 68 + c], s0);          // L[c][m] uniform
                s1 = fmaf(sS[(m + 1) * 68 + lane], sD[(m + 1) * 68 + c], s1);
            }
            if (m < c) s0 = fmaf(sS[m * 68 + lane], sD[m * 68 + c], s0);
            sS[c * 68 + lane] = (val - s0 - s1) * sInv[c];
        }
        __syncthreads();
        float* Aw = A + (long)rbase * 512 + k0;
#pragma unroll 8
        for (int r = 0; r < 64; r++)
            Aw[(long)r * 512 + lane] = sS[lane * 68 + r];
    }
}

// ---------------------------------------------------------------------------
// 5b) Trailing update: A22 -= L21 * L21^T, one 64x64 tile per block (fp32).
// ---------------------------------------------------------------------------
__global__ __launch_bounds__(256) void k_chol_update(float* __restrict__ A, int kb) {
    int k0 = kb * 64, base = k0 + 64;
    int idx = blockIdx.x, ti = 0;
    while (idx > ti) { idx -= ti + 1; ti++; }
    int tj = idx;
    int r0 = base + ti * 64, c0 = base + tj * 64;
    __shared__ float sI[64][65];
    __shared__ float sJ[64][65];
    int tid = threadIdx.x;
    int row = tid >> 4, c4 = (tid & 15) * 4;
#pragma unroll
    for (int q = 0; q < 4; q++) {
        int rr = row + q * 16;
        *(floatx4*)&sI[rr][c4] = *(const floatx4*)(A + (long)(r0 + rr) * 512 + k0 + c4);
        *(floatx4*)&sJ[rr][c4] = *(const floatx4*)(A + (long)(c0 + rr) * 512 + k0 + c4);
    }
    __syncthreads();
    int ri = (tid >> 4) * 4, cj = (tid & 15) * 4;
    float acc[4][4] = {};
    for (int k = 0; k < 64; k += 4) {
        floatx4 av[4], bv[4];
#pragma unroll
        for (int ii = 0; ii < 4; ii++) av[ii] = *(const floatx4*)&sI[ri + ii][k];
#pragma unroll
        for (int jj = 0; jj < 4; jj++) bv[jj] = *(const floatx4*)&sJ[cj + jj][k];
#pragma unroll
        for (int ii = 0; ii < 4; ii++)
#pragma unroll
            for (int jj = 0; jj < 4; jj++)
#pragma unroll
                for (int q = 0; q < 4; q++)
                    acc[ii][jj] = fmaf(av[ii][q], bv[jj][q], acc[ii][jj]);
    }
#pragma unroll
    for (int ii = 0; ii < 4; ii++) {
        float* dst = A + (long)(r0 + ri + ii) * 512 + c0 + cj;
        floatx4 old = *(const floatx4*)dst;
#pragma unroll
        for (int jj = 0; jj < 4; jj++) old[jj] -= acc[ii][jj];
        *(floatx4*)dst = old;
    }
}

// ---------------------------------------------------------------------------
// 6) out[i][d] = mean[d] + sum_{e<=d} z[i][e] * L[d][e]
// ---------------------------------------------------------------------------
__global__ __launch_bounds__(512) void k_output(const float* __restrict__ z,
                                                const float* __restrict__ A,
                                                const float* __restrict__ mu,
                                                float* __restrict__ out) {
    int i = blockIdx.x, d = threadIdx.x;
    __shared__ float sz[512];
    sz[d] = z[(long)i * 512 + d];
    __syncthreads();
    float mean = 0.f;
#pragma unroll
    for (int b = 0; b < 32; b++) mean += mu[b * 512 + d];
    mean *= (1.0f / 32.0f);
    const float* Lr = A + (long)d * 512;
    float acc = 0.f;
    int dmax = d + 1;
    int e4 = dmax & ~3;
    for (int e = 0; e < e4; e += 4) {
        floatx4 l = *(const floatx4*)(Lr + e);
        acc += l[0] * sz[e] + l[1] * sz[e + 1] + l[2] * sz[e + 2] + l[3] * sz[e + 3];
    }
    for (int e = e4; e < dmax; e++) acc += Lr[e] * sz[e];
    out[(long)i * 512 + d] = mean + acc;
}

// ---------------------------------------------------------------------------
extern "C" void kernel_launch(void* const* d_in, const int* in_sizes, int n_in,
                              void* d_out, int out_size, void* d_ws, size_t ws_size,
                              hipStream_t stream) {
    const float* x = (const float*)d_in[0];
    const float* z = (const float*)d_in[1];
    float* out = (float*)d_out;
    char* ws = (char*)d_ws;
    // ws layout: Xt 67108864B | mu 65536B | partial 16777216B | A 1048576B
    u16* Xt = (u16*)ws;
    float* mu = (float*)(ws + 67108864);
    float* partial = (float*)(ws + 67108864 + 65536);
    float* A = (float*)(ws + 67108864 + 65536 + 16777216);

    k_transpose<<<dim3(32, 8, 32), 256, 0, stream>>>(x, Xt);
    k_mu<<<4096, 256, 0, stream>>>(Xt, mu);
    k_gram<<<dim3(16, 10), 256, 0, stream>>>(Xt, partial);
    k_assemble<<<dim3(2, 512), 256, 0, stream>>>(partial, mu, A);
    for (int kb = 0; kb < 8; kb++) {
        int nb = 7 - kb;                 // 64-row stripes below the diagonal
        k_chol_panel<<<nb + 1, 64, 0, stream>>>(A, kb);
        int tiles = nb * (nb + 1) / 2;
        if (tiles > 0) k_chol_update<<<tiles, 256, 0, stream>>>(A, kb);
    }
    k_output<<<32, 512, 0, stream>>>(z, A, mu, out);
}

// Round 5
// 1047.202 us; speedup vs baseline: 1.2175x; 1.2175x over previous
//
#include <hip/hip_runtime.h>

#define Dn 512
#define Bn 32
#define Tn 2048
#define BT 65536   // Bn*Tn

typedef unsigned short u16;
typedef __attribute__((ext_vector_type(8))) short short8;   // 8 bf16 = 4 VGPRs (MFMA A/B frag)
typedef __attribute__((ext_vector_type(4))) float floatx4;  // MFMA C/D frag

__device__ __forceinline__ u16 f2bf(float f) {
    unsigned u = __float_as_uint(f);
    unsigned r = (u + 0x7FFFu + ((u >> 16) & 1u)) >> 16;    // RNE
    return (u16)r;
}
__device__ __forceinline__ float bf2f(u16 s) { return __uint_as_float(((unsigned)s) << 16); }

// ---------------------------------------------------------------------------
// 1) x[b][t][d] (f32) -> Xt[d][b*Tn+t] (bf16), LDS 64x64 tile transpose.
// ---------------------------------------------------------------------------
__global__ __launch_bounds__(256) void k_transpose(const float* __restrict__ x,
                                                   u16* __restrict__ Xt) {
    int tt = blockIdx.x;   // t-tile 0..31
    int dt = blockIdx.y;   // d-tile 0..7
    int b  = blockIdx.z;   // 0..31
    __shared__ u16 sT[64][68];  // [d][t], padded
    int tid = threadIdx.x;
    int row = tid >> 4;            // 0..15 (t)
    int c4  = (tid & 15) * 4;      // 0..60 (d)
    const float* src = x + ((long)b * Tn + (long)tt * 64) * Dn + dt * 64;
#pragma unroll
    for (int q = 0; q < 4; q++) {
        int r = row + q * 16;
        floatx4 v = *(const floatx4*)(src + (long)r * Dn + c4);
        sT[c4 + 0][r] = f2bf(v[0]);
        sT[c4 + 1][r] = f2bf(v[1]);
        sT[c4 + 2][r] = f2bf(v[2]);
        sT[c4 + 3][r] = f2bf(v[3]);
    }
    __syncthreads();
    int drow = tid >> 3;           // 0..31 (d)
    int koff = (tid & 7) * 8;      // 0..56 (t)
    long kout = (long)b * Tn + (long)tt * 64 + koff;
#pragma unroll
    for (int p = 0; p < 2; p++) {
        int dr = drow + p * 32;
        u16 tmp[8];
#pragma unroll
        for (int j = 0; j < 8; j++) tmp[j] = sT[dr][koff + j];
        *(short8*)(Xt + (long)(dt * 64 + dr) * BT + kout) = *(short8*)tmp;
    }
}

// ---------------------------------------------------------------------------
// 2) mu[b][d] = (1/T) sum_t Xt[d][b*Tn+t]   (wave per (b,d))
// ---------------------------------------------------------------------------
__global__ __launch_bounds__(256) void k_mu(const u16* __restrict__ Xt,
                                            float* __restrict__ mu) {
    int tid = threadIdx.x;
    int wave = tid >> 6, lane = tid & 63;
    int p = blockIdx.x * 4 + wave;      // 0..16383 == b*512+d
    int b = p >> 9, d = p & 511;
    const u16* src = Xt + (long)d * BT + (long)b * Tn;
    float s = 0.f;
#pragma unroll
    for (int c = 0; c < 4; c++) {
        short8 v = *(const short8*)(src + c * 512 + lane * 8);
#pragma unroll
        for (int j = 0; j < 8; j++) s += bf2f((u16)v[j]);
    }
#pragma unroll
    for (int off = 32; off; off >>= 1) s += __shfl_down(s, off, 64);
    if (lane == 0) mu[p] = s * (1.0f / Tn);
}

// ---------------------------------------------------------------------------
// 3) Gram partials: partial[chunk][d][e] = sum_{k in chunk} Xt[d][k]*Xt[e][k]
//    bf16 MFMA 16x16x32, 128x128 tile, BK=32, 16 K-chunks x 10 sym positions.
// ---------------------------------------------------------------------------
#define LDK 40   // padded LDS row stride (bf16 elems) to spread banks
__global__ __launch_bounds__(256) void k_gram(const u16* __restrict__ Xt,
                                              float* __restrict__ partial) {
    int chunk = blockIdx.x;             // 0..15 (K-chunk of 4096)
    int pos = blockIdx.y;               // 0..9 upper-block-triangle positions
    int di = (pos < 4) ? 0 : (pos < 7) ? 1 : (pos < 9) ? 2 : 3;
    int start = di * 4 - (di * (di - 1)) / 2;   // 0,4,7,9
    int ei = di + (pos - start);
    int d0 = di * 128, e0 = ei * 128;

    __shared__ u16 sA[128 * LDK];
    __shared__ u16 sB[128 * LDK];
    int tid = threadIdx.x;
    int wave = tid >> 6, lane = tid & 63;
    int wm = wave & 1, wn = wave >> 1;  // 2x2 waves over 128x128
    int lrow = tid >> 2;                // 0..63
    int lk = (tid & 3) * 8;             // 0,8,16,24
    const u16* gA = Xt + (long)(d0 + lrow) * BT + (long)chunk * 4096 + lk;
    const u16* gB = Xt + (long)(e0 + lrow) * BT + (long)chunk * 4096 + lk;
    int m = lane & 15, g = lane >> 4;

    floatx4 acc[4][4] = {};
    for (int kk = 0; kk < 4096; kk += 32) {
        short8 a0 = *(const short8*)(gA + kk);
        short8 a1 = *(const short8*)(gA + 64l * BT + kk);
        short8 b0 = *(const short8*)(gB + kk);
        short8 b1 = *(const short8*)(gB + 64l * BT + kk);
        __syncthreads();   // previous iteration's LDS reads done
        *(short8*)(sA + lrow * LDK + lk) = a0;
        *(short8*)(sA + (lrow + 64) * LDK + lk) = a1;
        *(short8*)(sB + lrow * LDK + lk) = b0;
        *(short8*)(sB + (lrow + 64) * LDK + lk) = b1;
        __syncthreads();
        short8 af[4], bf[4];
#pragma unroll
        for (int i = 0; i < 4; i++)
            af[i] = *(const short8*)(sA + (wm * 64 + i * 16 + m) * LDK + g * 8);
#pragma unroll
        for (int j = 0; j < 4; j++)
            bf[j] = *(const short8*)(sB + (wn * 64 + j * 16 + m) * LDK + g * 8);
#pragma unroll
        for (int i = 0; i < 4; i++)
#pragma unroll
            for (int j = 0; j < 4; j++)
                acc[i][j] = __builtin_amdgcn_mfma_f32_16x16x32_bf16(af[i], bf[j], acc[i][j], 0, 0, 0);
    }
    // C/D layout: col = lane&15, row = (lane>>4)*4 + reg   [m89-verified]
    float* P = partial + (long)chunk * (512l * 512);
    int col = lane & 15, rowg = (lane >> 4) * 4;
#pragma unroll
    for (int i = 0; i < 4; i++)
#pragma unroll
        for (int j = 0; j < 4; j++) {
            int rr = d0 + wm * 64 + i * 16 + rowg;
            int cc = e0 + wn * 64 + j * 16 + col;
#pragma unroll
            for (int r = 0; r < 4; r++) P[(long)(rr + r) * 512 + cc] = acc[i][j][r];
        }
}

// ---------------------------------------------------------------------------
// 4) cov[d][e] = (G[d][e] - T * sum_b mu[b,d]*mu[b,e]) / ((T-1)*B)
// ---------------------------------------------------------------------------
__global__ __launch_bounds__(256) void k_assemble(const float* __restrict__ partial,
                                                  const float* __restrict__ mu,
                                                  float* __restrict__ A) {
    int d = blockIdx.y;
    int e = blockIdx.x * 256 + threadIdx.x;
    int bd = d >> 7, be = e >> 7;
    long idx = (bd <= be) ? ((long)d * 512 + e) : ((long)e * 512 + d);  // symmetric mirror
    float s = 0.f;
#pragma unroll
    for (int c = 0; c < 16; c++) s += partial[c * (512l * 512) + idx];
    float msum = 0.f;
#pragma unroll
    for (int b = 0; b < 32; b++) msum += mu[b * 512 + d] * mu[b * 512 + e];
    A[(long)d * 512 + e] = (s - (float)Tn * msum) * (1.0f / ((Tn - 1.0f) * Bn));
}

// ---------------------------------------------------------------------------
// 5a) Cholesky panel, 256 threads = 4 waves.
//     Round-4 lesson: rolled read->fma->write LDS loops serialize at the
//     full LDS round trip (lgkmcnt in-order queue) -> 145 cyc/elem. Fix:
//     (a) 4 waves split the rank-1 update (16 columns each),
//     (b) all reads of a k-step batched as NAMED scalars before any write,
//     (c) row-major LDS with odd stride 69 -> conflict-free both directions.
//     Tasks per wave: task0 = diag writeback, task1..nb = one 64-row L21
//     stripe (left-looking solve, xprev register breaks the c->c+1 chain).
// ---------------------------------------------------------------------------
#define SDS 69   // odd LDS stride (floats)
__global__ __launch_bounds__(256) void k_chol_panel(float* __restrict__ A, int kb, int nb) {
    const int k0 = kb * 64;
    const int tid = threadIdx.x;
    const int lane = tid & 63;
    const int wv = tid >> 6;
    __shared__ float sD[64 * SDS];          // diag block, row-major sD[r*69+c]
    __shared__ float sS[4][64 * SDS];       // per-wave stripe buffers
    __shared__ float sInv[64];

    // ---- stage diag block (coalesced; LDS writes conflict-free) ----
    {
        const float* Ad = A + (long)k0 * 512 + k0;
        int rb = wv * 16;
#pragma unroll 4
        for (int r = 0; r < 16; r++)
            sD[(rb + r) * SDS + lane] = Ad[(long)(rb + r) * 512 + lane];
    }
    __syncthreads();

    // ---- factor 64x64, right-looking; wave wv owns columns [16wv,16wv+16) ----
    const int c0 = wv * 16;
    for (int k = 0; k < 64; k++) {
        float akk = sD[k * SDS + k];                 // uniform
        float sd = sqrtf(akk);
        float inv = 1.0f / sd;
        float ark = sD[lane * SDS + k];              // own row, column k (raw)
        float lik = (lane == k) ? sd : ark * inv;
        // batched raw reads (named scalars; issued before any write)
#define RD(i) float x##i = sD[lane * SDS + c0 + i]; float y##i = sD[(c0 + i) * SDS + k];
        RD(0) RD(1) RD(2) RD(3) RD(4) RD(5) RD(6) RD(7)
        RD(8) RD(9) RD(10) RD(11) RD(12) RD(13) RD(14) RD(15)
#undef RD
        __syncthreads();
        if (wv == (k >> 4)) sD[lane * SDS + k] = lik;   // finalize column k
#define UPD(i) if (c0 + i > k) sD[lane * SDS + c0 + i] = fmaf(-lik, y##i * inv, x##i);
        UPD(0) UPD(1) UPD(2) UPD(3) UPD(4) UPD(5) UPD(6) UPD(7)
        UPD(8) UPD(9) UPD(10) UPD(11) UPD(12) UPD(13) UPD(14) UPD(15)
#undef UPD
        __syncthreads();
    }
    if (tid < 64) sInv[tid] = 1.0f / sD[tid * SDS + tid];
    __syncthreads();

    // ---- per-wave task ----
    int task = blockIdx.x * 4 + wv;
    if (task == 0) {
        // write back factored diag (upper-junk never read downstream)
        float* Ad = A + (long)k0 * 512 + k0;
        for (int r = 0; r < 64; r++)
            Ad[(long)r * 512 + lane] = sD[r * SDS + lane];
    } else if (task <= nb) {
        int rbase = k0 + 64 + (task - 1) * 64;
        float* sSw = sS[wv];
        const float* As = A + (long)rbase * 512 + k0;
        for (int r = 0; r < 64; r++)
            sSw[r * SDS + lane] = As[(long)r * 512 + lane];
        // no cross-wave deps below; lane = row of the stripe
        // left-looking forward substitution: x_c = (a_c - sum_{m<c} x_m*L[c][m])/L[c][c]
        float xprev = 0.0f;
        for (int c = 0; c < 64; c++) {
            float acc0 = 0.f, acc1 = 0.f, acc2 = 0.f, acc3 = 0.f;
            int mend = c - 1;            // m = c-1 handled via xprev register
            int m = 0;
            for (; m + 3 < mend; m += 4) {
                float a0 = sSw[lane * SDS + m + 0], l0 = sD[c * SDS + m + 0];
                float a1 = sSw[lane * SDS + m + 1], l1 = sD[c * SDS + m + 1];
                float a2 = sSw[lane * SDS + m + 2], l2 = sD[c * SDS + m + 2];
                float a3 = sSw[lane * SDS + m + 3], l3 = sD[c * SDS + m + 3];
                acc0 = fmaf(a0, l0, acc0);
                acc1 = fmaf(a1, l1, acc1);
                acc2 = fmaf(a2, l2, acc2);
                acc3 = fmaf(a3, l3, acc3);
            }
            for (; m < mend; m++)
                acc0 = fmaf(sSw[lane * SDS + m], sD[c * SDS + m], acc0);
            float acc = (acc0 + acc1) + (acc2 + acc3);
            if (c > 0) acc = fmaf(xprev, sD[c * SDS + (c - 1)], acc);
            float xc = (sSw[lane * SDS + c] - acc) * sInv[c];
            sSw[lane * SDS + c] = xc;
            xprev = xc;
        }
        float* Aw = A + (long)rbase * 512 + k0;
        for (int r = 0; r < 64; r++)
            Aw[(long)r * 512 + lane] = sSw[r * SDS + lane];
    }
}

// ---------------------------------------------------------------------------
// 5b) Trailing update: A22 -= L21 * L21^T, one 64x64 tile per block (fp32).
// ---------------------------------------------------------------------------
__global__ __launch_bounds__(256) void k_chol_update(float* __restrict__ A, int kb) {
    int k0 = kb * 64, base = k0 + 64;
    int idx = blockIdx.x, ti = 0;
    while (idx > ti) { idx -= ti + 1; ti++; }
    int tj = idx;
    int r0 = base + ti * 64, c0 = base + tj * 64;
    __shared__ float sI[64][65];
    __shared__ float sJ[64][65];
    int tid = threadIdx.x;
    int row = tid >> 4, c4 = (tid & 15) * 4;
#pragma unroll
    for (int q = 0; q < 4; q++) {
        int rr = row + q * 16;
        *(floatx4*)&sI[rr][c4] = *(const floatx4*)(A + (long)(r0 + rr) * 512 + k0 + c4);
        *(floatx4*)&sJ[rr][c4] = *(const floatx4*)(A + (long)(c0 + rr) * 512 + k0 + c4);
    }
    __syncthreads();
    int ri = (tid >> 4) * 4, cj = (tid & 15) * 4;
    float acc[4][4] = {};
    for (int k = 0; k < 64; k += 4) {
        floatx4 av[4], bv[4];
#pragma unroll
        for (int ii = 0; ii < 4; ii++) av[ii] = *(const floatx4*)&sI[ri + ii][k];
#pragma unroll
        for (int jj = 0; jj < 4; jj++) bv[jj] = *(const floatx4*)&sJ[cj + jj][k];
#pragma unroll
        for (int ii = 0; ii < 4; ii++)
#pragma unroll
            for (int jj = 0; jj < 4; jj++)
#pragma unroll
                for (int q = 0; q < 4; q++)
                    acc[ii][jj] = fmaf(av[ii][q], bv[jj][q], acc[ii][jj]);
    }
#pragma unroll
    for (int ii = 0; ii < 4; ii++) {
        float* dst = A + (long)(r0 + ri + ii) * 512 + c0 + cj;
        floatx4 old = *(const floatx4*)dst;
#pragma unroll
        for (int jj = 0; jj < 4; jj++) old[jj] -= acc[ii][jj];
        *(floatx4*)dst = old;
    }
}

// ---------------------------------------------------------------------------
// 6) out[i][d] = mean[d] + sum_{e<=d} z[i][e] * L[d][e]
// ---------------------------------------------------------------------------
__global__ __launch_bounds__(512) void k_output(const float* __restrict__ z,
                                                const float* __restrict__ A,
                                                const float* __restrict__ mu,
                                                float* __restrict__ out) {
    int i = blockIdx.x, d = threadIdx.x;
    __shared__ float sz[512];
    sz[d] = z[(long)i * 512 + d];
    __syncthreads();
    float mean = 0.f;
#pragma unroll
    for (int b = 0; b < 32; b++) mean += mu[b * 512 + d];
    mean *= (1.0f / 32.0f);
    const float* Lr = A + (long)d * 512;
    float acc = 0.f;
    int dmax = d + 1;
    int e4 = dmax & ~3;
    for (int e = 0; e < e4; e += 4) {
        floatx4 l = *(const floatx4*)(Lr + e);
        acc += l[0] * sz[e] + l[1] * sz[e + 1] + l[2] * sz[e + 2] + l[3] * sz[e + 3];
    }
    for (int e = e4; e < dmax; e++) acc += Lr[e] * sz[e];
    out[(long)i * 512 + d] = mean + acc;
}

// ---------------------------------------------------------------------------
extern "C" void kernel_launch(void* const* d_in, const int* in_sizes, int n_in,
                              void* d_out, int out_size, void* d_ws, size_t ws_size,
                              hipStream_t stream) {
    const float* x = (const float*)d_in[0];
    const float* z = (const float*)d_in[1];
    float* out = (float*)d_out;
    char* ws = (char*)d_ws;
    // ws layout: Xt 67108864B | mu 65536B | partial 16777216B | A 1048576B
    u16* Xt = (u16*)ws;
    float* mu = (float*)(ws + 67108864);
    float* partial = (float*)(ws + 67108864 + 65536);
    float* A = (float*)(ws + 67108864 + 65536 + 16777216);

    k_transpose<<<dim3(32, 8, 32), 256, 0, stream>>>(x, Xt);
    k_mu<<<4096, 256, 0, stream>>>(Xt, mu);
    k_gram<<<dim3(16, 10), 256, 0, stream>>>(Xt, partial);
    k_assemble<<<dim3(2, 512), 256, 0, stream>>>(partial, mu, A);
    for (int kb = 0; kb < 8; kb++) {
        int nb = 7 - kb;                 // 64-row stripes below the diagonal
        int tasks = nb + 1;              // diag writeback + nb stripes
        int pg = (tasks + 3) / 4;        // 4 wave-tasks per block
        k_chol_panel<<<pg, 256, 0, stream>>>(A, kb, nb);
        int tiles = nb * (nb + 1) / 2;
        if (tiles > 0) k_chol_update<<<tiles, 256, 0, stream>>>(A, kb);
    }
    k_output<<<32, 512, 0, stream>>>(z, A, mu, out);
}

// Round 6
// 725.707 us; speedup vs baseline: 1.7569x; 1.4430x over previous
//
#include <hip/hip_runtime.h>

#define Dn 512
#define Bn 32
#define Tn 2048
#define BT 65536   // Bn*Tn

typedef unsigned short u16;
typedef __attribute__((ext_vector_type(8))) short short8;   // 8 bf16 = 4 VGPRs (MFMA A/B frag)
typedef __attribute__((ext_vector_type(4))) float floatx4;  // MFMA C/D frag

__device__ __forceinline__ u16 f2bf(float f) {
    unsigned u = __float_as_uint(f);
    unsigned r = (u + 0x7FFFu + ((u >> 16) & 1u)) >> 16;    // RNE
    return (u16)r;
}
__device__ __forceinline__ float bf2f(u16 s) { return __uint_as_float(((unsigned)s) << 16); }

// 64-entry preprocessor repeat lists (rounds 1-5 lesson: indexed per-thread
// arrays go to scratch; LDS working sets are issue/latency bound. Named
// scalars + macro-unrolled straight-line code is the only register path.)
#define REP64(X) X(0) X(1) X(2) X(3) X(4) X(5) X(6) X(7) X(8) X(9) X(10) X(11) X(12) X(13) X(14) X(15) \
    X(16) X(17) X(18) X(19) X(20) X(21) X(22) X(23) X(24) X(25) X(26) X(27) X(28) X(29) X(30) X(31) \
    X(32) X(33) X(34) X(35) X(36) X(37) X(38) X(39) X(40) X(41) X(42) X(43) X(44) X(45) X(46) X(47) \
    X(48) X(49) X(50) X(51) X(52) X(53) X(54) X(55) X(56) X(57) X(58) X(59) X(60) X(61) X(62) X(63)
#define REPJ(OP, K) OP(K,0) OP(K,1) OP(K,2) OP(K,3) OP(K,4) OP(K,5) OP(K,6) OP(K,7) OP(K,8) OP(K,9) \
    OP(K,10) OP(K,11) OP(K,12) OP(K,13) OP(K,14) OP(K,15) OP(K,16) OP(K,17) OP(K,18) OP(K,19) \
    OP(K,20) OP(K,21) OP(K,22) OP(K,23) OP(K,24) OP(K,25) OP(K,26) OP(K,27) OP(K,28) OP(K,29) \
    OP(K,30) OP(K,31) OP(K,32) OP(K,33) OP(K,34) OP(K,35) OP(K,36) OP(K,37) OP(K,38) OP(K,39) \
    OP(K,40) OP(K,41) OP(K,42) OP(K,43) OP(K,44) OP(K,45) OP(K,46) OP(K,47) OP(K,48) OP(K,49) \
    OP(K,50) OP(K,51) OP(K,52) OP(K,53) OP(K,54) OP(K,55) OP(K,56) OP(K,57) OP(K,58) OP(K,59) \
    OP(K,60) OP(K,61) OP(K,62) OP(K,63)
#define REPJA(OP, C) OP(C,0,0) OP(C,1,1) OP(C,2,2) OP(C,3,3) OP(C,4,0) OP(C,5,1) OP(C,6,2) OP(C,7,3) \
    OP(C,8,0) OP(C,9,1) OP(C,10,2) OP(C,11,3) OP(C,12,0) OP(C,13,1) OP(C,14,2) OP(C,15,3) \
    OP(C,16,0) OP(C,17,1) OP(C,18,2) OP(C,19,3) OP(C,20,0) OP(C,21,1) OP(C,22,2) OP(C,23,3) \
    OP(C,24,0) OP(C,25,1) OP(C,26,2) OP(C,27,3) OP(C,28,0) OP(C,29,1) OP(C,30,2) OP(C,31,3) \
    OP(C,32,0) OP(C,33,1) OP(C,34,2) OP(C,35,3) OP(C,36,0) OP(C,37,1) OP(C,38,2) OP(C,39,3) \
    OP(C,40,0) OP(C,41,1) OP(C,42,2) OP(C,43,3) OP(C,44,0) OP(C,45,1) OP(C,46,2) OP(C,47,3) \
    OP(C,48,0) OP(C,49,1) OP(C,50,2) OP(C,51,3) OP(C,52,0) OP(C,53,1) OP(C,54,2) OP(C,55,3) \
    OP(C,56,0) OP(C,57,1) OP(C,58,2) OP(C,59,3) OP(C,60,0) OP(C,61,1) OP(C,62,2) OP(C,63,3)

// ---------------------------------------------------------------------------
// 1) x[b][t][d] (f32) -> Xt[d][b*Tn+t] (bf16), LDS 64x64 tile transpose.
// ---------------------------------------------------------------------------
__global__ __launch_bounds__(256) void k_transpose(const float* __restrict__ x,
                                                   u16* __restrict__ Xt) {
    int tt = blockIdx.x;   // t-tile 0..31
    int dt = blockIdx.y;   // d-tile 0..7
    int b  = blockIdx.z;   // 0..31
    __shared__ u16 sT[64][68];  // [d][t], padded
    int tid = threadIdx.x;
    int row = tid >> 4;            // 0..15 (t)
    int c4  = (tid & 15) * 4;      // 0..60 (d)
    const float* src = x + ((long)b * Tn + (long)tt * 64) * Dn + dt * 64;
#pragma unroll
    for (int q = 0; q < 4; q++) {
        int r = row + q * 16;
        floatx4 v = *(const floatx4*)(src + (long)r * Dn + c4);
        sT[c4 + 0][r] = f2bf(v[0]);
        sT[c4 + 1][r] = f2bf(v[1]);
        sT[c4 + 2][r] = f2bf(v[2]);
        sT[c4 + 3][r] = f2bf(v[3]);
    }
    __syncthreads();
    int drow = tid >> 3;           // 0..31 (d)
    int koff = (tid & 7) * 8;      // 0..56 (t)
    long kout = (long)b * Tn + (long)tt * 64 + koff;
#pragma unroll
    for (int p = 0; p < 2; p++) {
        int dr = drow + p * 32;
        u16 tmp[8];
#pragma unroll
        for (int j = 0; j < 8; j++) tmp[j] = sT[dr][koff + j];
        *(short8*)(Xt + (long)(dt * 64 + dr) * BT + kout) = *(short8*)tmp;
    }
}

// ---------------------------------------------------------------------------
// 2) mu[b][d] = (1/T) sum_t Xt[d][b*Tn+t]   (wave per (b,d))
// ---------------------------------------------------------------------------
__global__ __launch_bounds__(256) void k_mu(const u16* __restrict__ Xt,
                                            float* __restrict__ mu) {
    int tid = threadIdx.x;
    int wave = tid >> 6, lane = tid & 63;
    int p = blockIdx.x * 4 + wave;      // 0..16383 == b*512+d
    int b = p >> 9, d = p & 511;
    const u16* src = Xt + (long)d * BT + (long)b * Tn;
    float s = 0.f;
#pragma unroll
    for (int c = 0; c < 4; c++) {
        short8 v = *(const short8*)(src + c * 512 + lane * 8);
#pragma unroll
        for (int j = 0; j < 8; j++) s += bf2f((u16)v[j]);
    }
#pragma unroll
    for (int off = 32; off; off >>= 1) s += __shfl_down(s, off, 64);
    if (lane == 0) mu[p] = s * (1.0f / Tn);
}

// ---------------------------------------------------------------------------
// 3) Gram partials: partial[chunk][d][e] = sum_{k in chunk} Xt[d][k]*Xt[e][k]
//    bf16 MFMA 16x16x32, 128x128 tile, BK=32, 16 K-chunks x 10 sym positions.
// ---------------------------------------------------------------------------
#define LDK 40   // padded LDS row stride (bf16 elems) to spread banks
__global__ __launch_bounds__(256) void k_gram(const u16* __restrict__ Xt,
                                              float* __restrict__ partial) {
    int chunk = blockIdx.x;             // 0..15 (K-chunk of 4096)
    int pos = blockIdx.y;               // 0..9 upper-block-triangle positions
    int di = (pos < 4) ? 0 : (pos < 7) ? 1 : (pos < 9) ? 2 : 3;
    int start = di * 4 - (di * (di - 1)) / 2;   // 0,4,7,9
    int ei = di + (pos - start);
    int d0 = di * 128, e0 = ei * 128;

    __shared__ u16 sA[128 * LDK];
    __shared__ u16 sB[128 * LDK];
    int tid = threadIdx.x;
    int wave = tid >> 6, lane = tid & 63;
    int wm = wave & 1, wn = wave >> 1;  // 2x2 waves over 128x128
    int lrow = tid >> 2;                // 0..63
    int lk = (tid & 3) * 8;             // 0,8,16,24
    const u16* gA = Xt + (long)(d0 + lrow) * BT + (long)chunk * 4096 + lk;
    const u16* gB = Xt + (long)(e0 + lrow) * BT + (long)chunk * 4096 + lk;
    int m = lane & 15, g = lane >> 4;

    floatx4 acc[4][4] = {};
    for (int kk = 0; kk < 4096; kk += 32) {
        short8 a0 = *(const short8*)(gA + kk);
        short8 a1 = *(const short8*)(gA + 64l * BT + kk);
        short8 b0 = *(const short8*)(gB + kk);
        short8 b1 = *(const short8*)(gB + 64l * BT + kk);
        __syncthreads();   // previous iteration's LDS reads done
        *(short8*)(sA + lrow * LDK + lk) = a0;
        *(short8*)(sA + (lrow + 64) * LDK + lk) = a1;
        *(short8*)(sB + lrow * LDK + lk) = b0;
        *(short8*)(sB + (lrow + 64) * LDK + lk) = b1;
        __syncthreads();
        short8 af[4], bf[4];
#pragma unroll
        for (int i = 0; i < 4; i++)
            af[i] = *(const short8*)(sA + (wm * 64 + i * 16 + m) * LDK + g * 8);
#pragma unroll
        for (int j = 0; j < 4; j++)
            bf[j] = *(const short8*)(sB + (wn * 64 + j * 16 + m) * LDK + g * 8);
#pragma unroll
        for (int i = 0; i < 4; i++)
#pragma unroll
            for (int j = 0; j < 4; j++)
                acc[i][j] = __builtin_amdgcn_mfma_f32_16x16x32_bf16(af[i], bf[j], acc[i][j], 0, 0, 0);
    }
    // C/D layout: col = lane&15, row = (lane>>4)*4 + reg   [m89-verified]
    float* P = partial + (long)chunk * (512l * 512);
    int col = lane & 15, rowg = (lane >> 4) * 4;
#pragma unroll
    for (int i = 0; i < 4; i++)
#pragma unroll
        for (int j = 0; j < 4; j++) {
            int rr = d0 + wm * 64 + i * 16 + rowg;
            int cc = e0 + wn * 64 + j * 16 + col;
#pragma unroll
            for (int r = 0; r < 4; r++) P[(long)(rr + r) * 512 + cc] = acc[i][j][r];
        }
}

// ---------------------------------------------------------------------------
// 4) cov[d][e] = (G[d][e] - T * sum_b mu[b,d]*mu[b,e]) / ((T-1)*B)
// ---------------------------------------------------------------------------
__global__ __launch_bounds__(256) void k_assemble(const float* __restrict__ partial,
                                                  const float* __restrict__ mu,
                                                  float* __restrict__ A) {
    int d = blockIdx.y;
    int e = blockIdx.x * 256 + threadIdx.x;
    int bd = d >> 7, be = e >> 7;
    long idx = (bd <= be) ? ((long)d * 512 + e) : ((long)e * 512 + d);  // symmetric mirror
    float s = 0.f;
#pragma unroll
    for (int c = 0; c < 16; c++) s += partial[c * (512l * 512) + idx];
    float msum = 0.f;
#pragma unroll
    for (int b = 0; b < 32; b++) msum += mu[b * 512 + d] * mu[b * 512 + e];
    A[(long)d * 512 + e] = (s - (float)Tn * msum) * (1.0f / ((Tn - 1.0f) * Bn));
}

// ---------------------------------------------------------------------------
// 5a) Diag factor: ONE wave, row of the 64x64 block in 64 NAMED registers,
//     elimination fully macro-unrolled (literal lane indices -> v_readlane;
//     'if (J>K)' folds at compile time). Rows < K produce junk in the upper
//     triangle which is never read downstream. Writes L11 + invD.
// ---------------------------------------------------------------------------
__global__ __launch_bounds__(64, 1) void k_chol_diag(float* __restrict__ A,
                                                     float* __restrict__ invD,
                                                     int kb) {
    const int k0 = kb * 64;
    const int lane = threadIdx.x;
    __shared__ float sT[64 * 65];
    const float* Ad = A + (long)k0 * 512 + k0;
#pragma unroll 8
    for (int r = 0; r < 64; r++) sT[r * 65 + lane] = Ad[(long)r * 512 + lane];
    __syncthreads();
#define DECLR(J) float r##J = sT[lane * 65 + (J)];
    REP64(DECLR)
#undef DECLR
    float vinv = 0.f;
#define UPDJ(K, J) if ((J) > (K)) r##J = fmaf(-lik, __shfl(lik, (J), 64), r##J);
#define STEP(K) { float akk = __shfl(r##K, (K), 64); float sd = sqrtf(akk); \
                  float inv = 1.0f / sd; float lik = (lane == (K)) ? sd : r##K * inv; \
                  r##K = lik; if (lane == (K)) vinv = inv; REPJ(UPDJ, K) }
    REP64(STEP)
#undef STEP
#undef UPDJ
    invD[kb * 64 + lane] = vinv;
#define STORER(J) sT[lane * 65 + (J)] = r##J;
    REP64(STORER)
#undef STORER
    __syncthreads();
    float* Aw = A + (long)k0 * 512 + k0;
#pragma unroll 8
    for (int r = 0; r < 64; r++) Aw[(long)r * 512 + lane] = sT[r * 65 + lane];
}

// ---------------------------------------------------------------------------
// 5b) TRSM: one wave per 64-row stripe. Stripe row in 64 NAMED registers,
//     left-looking solve; L11 entries are wave-uniform LDS broadcasts (each
//     of the 2016 entries read exactly once); 4 interleaved accumulators
//     break the fma dependency chain. Stage/writeback via LDS for coalescing.
// ---------------------------------------------------------------------------
__global__ __launch_bounds__(64, 1) void k_chol_trsm(float* __restrict__ A,
                                                     const float* __restrict__ invD,
                                                     int kb) {
    const int k0 = kb * 64;
    const int lane = threadIdx.x;
    __shared__ float sD[64 * 65];
    __shared__ float sS[64 * 65];
    __shared__ float sInv[64];
    const float* Ad = A + (long)k0 * 512 + k0;
#pragma unroll 8
    for (int r = 0; r < 64; r++) sD[r * 65 + lane] = Ad[(long)r * 512 + lane];
    sInv[lane] = invD[kb * 64 + lane];
    int rbase = k0 + 64 + blockIdx.x * 64;
    const float* As = A + (long)rbase * 512 + k0;
#pragma unroll 8
    for (int r = 0; r < 64; r++) sS[r * 65 + lane] = As[(long)r * 512 + lane];
    __syncthreads();
#define DECLA(J) float a##J = sS[lane * 65 + (J)];
    REP64(DECLA)
#undef DECLA
#define TUPD(C, M, AC) if ((M) < (C)) acc##AC = fmaf(a##M, sD[(C) * 65 + (M)], acc##AC);
#define TSTEP(C) { float acc0 = 0.f, acc1 = 0.f, acc2 = 0.f, acc3 = 0.f; REPJA(TUPD, C) \
                   a##C = (a##C - ((acc0 + acc1) + (acc2 + acc3))) * sInv[(C)]; }
    REP64(TSTEP)
#undef TSTEP
#undef TUPD
#define STOREA(J) sS[lane * 65 + (J)] = a##J;
    REP64(STOREA)
#undef STOREA
    __syncthreads();
    float* Aw = A + (long)rbase * 512 + k0;
#pragma unroll 8
    for (int r = 0; r < 64; r++) Aw[(long)r * 512 + lane] = sS[r * 65 + lane];
}

// ---------------------------------------------------------------------------
// 5c) Trailing update: A22 -= L21 * L21^T, one 64x64 tile per block (fp32).
// ---------------------------------------------------------------------------
__global__ __launch_bounds__(256) void k_chol_update(float* __restrict__ A, int kb) {
    int k0 = kb * 64, base = k0 + 64;
    int idx = blockIdx.x, ti = 0;
    while (idx > ti) { idx -= ti + 1; ti++; }
    int tj = idx;
    int r0 = base + ti * 64, c0 = base + tj * 64;
    __shared__ float sI[64][65];
    __shared__ float sJ[64][65];
    int tid = threadIdx.x;
    int row = tid >> 4, c4 = (tid & 15) * 4;
#pragma unroll
    for (int q = 0; q < 4; q++) {
        int rr = row + q * 16;
        *(floatx4*)&sI[rr][c4] = *(const floatx4*)(A + (long)(r0 + rr) * 512 + k0 + c4);
        *(floatx4*)&sJ[rr][c4] = *(const floatx4*)(A + (long)(c0 + rr) * 512 + k0 + c4);
    }
    __syncthreads();
    int ri = (tid >> 4) * 4, cj = (tid & 15) * 4;
    float acc[4][4] = {};
    for (int k = 0; k < 64; k += 4) {
        floatx4 av[4], bv[4];
#pragma unroll
        for (int ii = 0; ii < 4; ii++) av[ii] = *(const floatx4*)&sI[ri + ii][k];
#pragma unroll
        for (int jj = 0; jj < 4; jj++) bv[jj] = *(const floatx4*)&sJ[cj + jj][k];
#pragma unroll
        for (int ii = 0; ii < 4; ii++)
#pragma unroll
            for (int jj = 0; jj < 4; jj++)
#pragma unroll
                for (int q = 0; q < 4; q++)
                    acc[ii][jj] = fmaf(av[ii][q], bv[jj][q], acc[ii][jj]);
    }
#pragma unroll
    for (int ii = 0; ii < 4; ii++) {
        float* dst = A + (long)(r0 + ri + ii) * 512 + c0 + cj;
        floatx4 old = *(const floatx4*)dst;
#pragma unroll
        for (int jj = 0; jj < 4; jj++) old[jj] -= acc[ii][jj];
        *(floatx4*)dst = old;
    }
}

// ---------------------------------------------------------------------------
// 6) out[i][d] = mean[d] + sum_{e<=d} z[i][e] * L[d][e]
// ---------------------------------------------------------------------------
__global__ __launch_bounds__(512) void k_output(const float* __restrict__ z,
                                                const float* __restrict__ A,
                                                const float* __restrict__ mu,
                                                float* __restrict__ out) {
    int i = blockIdx.x, d = threadIdx.x;
    __shared__ float sz[512];
    sz[d] = z[(long)i * 512 + d];
    __syncthreads();
    float mean = 0.f;
#pragma unroll
    for (int b = 0; b < 32; b++) mean += mu[b * 512 + d];
    mean *= (1.0f / 32.0f);
    const float* Lr = A + (long)d * 512;
    float acc = 0.f;
    int dmax = d + 1;
    int e4 = dmax & ~3;
    for (int e = 0; e < e4; e += 4) {
        floatx4 l = *(const floatx4*)(Lr + e);
        acc += l[0] * sz[e] + l[1] * sz[e + 1] + l[2] * sz[e + 2] + l[3] * sz[e + 3];
    }
    for (int e = e4; e < dmax; e++) acc += Lr[e] * sz[e];
    out[(long)i * 512 + d] = mean + acc;
}

// ---------------------------------------------------------------------------
extern "C" void kernel_launch(void* const* d_in, const int* in_sizes, int n_in,
                              void* d_out, int out_size, void* d_ws, size_t ws_size,
                              hipStream_t stream) {
    const float* x = (const float*)d_in[0];
    const float* z = (const float*)d_in[1];
    float* out = (float*)d_out;
    char* ws = (char*)d_ws;
    // ws layout: Xt 67108864B | mu 65536B | partial 16777216B | A 1048576B | invD 2048B
    u16* Xt = (u16*)ws;
    float* mu = (float*)(ws + 67108864);
    float* partial = (float*)(ws + 67108864 + 65536);
    float* A = (float*)(ws + 67108864 + 65536 + 16777216);
    float* invD = (float*)(ws + 67108864 + 65536 + 16777216 + 1048576);

    k_transpose<<<dim3(32, 8, 32), 256, 0, stream>>>(x, Xt);
    k_mu<<<4096, 256, 0, stream>>>(Xt, mu);
    k_gram<<<dim3(16, 10), 256, 0, stream>>>(Xt, partial);
    k_assemble<<<dim3(2, 512), 256, 0, stream>>>(partial, mu, A);
    for (int kb = 0; kb < 8; kb++) {
        k_chol_diag<<<1, 64, 0, stream>>>(A, invD, kb);
        int nb = 7 - kb;
        if (nb > 0) k_chol_trsm<<<nb, 64, 0, stream>>>(A, invD, kb);
        int tiles = nb * (nb + 1) / 2;
        if (tiles > 0) k_chol_update<<<tiles, 256, 0, stream>>>(A, kb);
    }
    k_output<<<32, 512, 0, stream>>>(z, A, mu, out);
}

// Round 7
// 673.988 us; speedup vs baseline: 1.8917x; 1.0767x over previous
//
#include <hip/hip_runtime.h>

#define Dn 512
#define Bn 32
#define Tn 2048
#define BT 65536   // Bn*Tn

typedef unsigned short u16;
typedef __attribute__((ext_vector_type(8))) short short8;   // 8 bf16 = 4 VGPRs (MFMA A/B frag)
typedef __attribute__((ext_vector_type(4))) float floatx4;  // MFMA C/D frag

__device__ __forceinline__ u16 f2bf(float f) {
    unsigned u = __float_as_uint(f);
    unsigned r = (u + 0x7FFFu + ((u >> 16) & 1u)) >> 16;    // RNE
    return (u16)r;
}
__device__ __forceinline__ float bf2f(u16 s) { return __uint_as_float(((unsigned)s) << 16); }

// Preprocessor repeat lists. Lessons r1-r6: (a) indexed per-thread arrays ->
// scratch; (b) LDS working sets -> issue-bound; (c) shfl/LDS-read consumed
// immediately by its fma -> wait-per-use serialization (~25-30 cyc/elem).
// Named scalars + BATCHED loads/shuffles before the fma pass is the pattern.
#define REP64(X) X(0) X(1) X(2) X(3) X(4) X(5) X(6) X(7) X(8) X(9) X(10) X(11) X(12) X(13) X(14) X(15) \
    X(16) X(17) X(18) X(19) X(20) X(21) X(22) X(23) X(24) X(25) X(26) X(27) X(28) X(29) X(30) X(31) \
    X(32) X(33) X(34) X(35) X(36) X(37) X(38) X(39) X(40) X(41) X(42) X(43) X(44) X(45) X(46) X(47) \
    X(48) X(49) X(50) X(51) X(52) X(53) X(54) X(55) X(56) X(57) X(58) X(59) X(60) X(61) X(62) X(63)
#define REPJ(OP, K) OP(K,0) OP(K,1) OP(K,2) OP(K,3) OP(K,4) OP(K,5) OP(K,6) OP(K,7) OP(K,8) OP(K,9) \
    OP(K,10) OP(K,11) OP(K,12) OP(K,13) OP(K,14) OP(K,15) OP(K,16) OP(K,17) OP(K,18) OP(K,19) \
    OP(K,20) OP(K,21) OP(K,22) OP(K,23) OP(K,24) OP(K,25) OP(K,26) OP(K,27) OP(K,28) OP(K,29) \
    OP(K,30) OP(K,31) OP(K,32) OP(K,33) OP(K,34) OP(K,35) OP(K,36) OP(K,37) OP(K,38) OP(K,39) \
    OP(K,40) OP(K,41) OP(K,42) OP(K,43) OP(K,44) OP(K,45) OP(K,46) OP(K,47) OP(K,48) OP(K,49) \
    OP(K,50) OP(K,51) OP(K,52) OP(K,53) OP(K,54) OP(K,55) OP(K,56) OP(K,57) OP(K,58) OP(K,59) \
    OP(K,60) OP(K,61) OP(K,62) OP(K,63)
// 64 (M, Mq=M/4, e=M%4) triples with a carried C
#define REPQ(OP, C) OP(C,0,0,0) OP(C,1,0,1) OP(C,2,0,2) OP(C,3,0,3) OP(C,4,1,0) OP(C,5,1,1) OP(C,6,1,2) OP(C,7,1,3) \
    OP(C,8,2,0) OP(C,9,2,1) OP(C,10,2,2) OP(C,11,2,3) OP(C,12,3,0) OP(C,13,3,1) OP(C,14,3,2) OP(C,15,3,3) \
    OP(C,16,4,0) OP(C,17,4,1) OP(C,18,4,2) OP(C,19,4,3) OP(C,20,5,0) OP(C,21,5,1) OP(C,22,5,2) OP(C,23,5,3) \
    OP(C,24,6,0) OP(C,25,6,1) OP(C,26,6,2) OP(C,27,6,3) OP(C,28,7,0) OP(C,29,7,1) OP(C,30,7,2) OP(C,31,7,3) \
    OP(C,32,8,0) OP(C,33,8,1) OP(C,34,8,2) OP(C,35,8,3) OP(C,36,9,0) OP(C,37,9,1) OP(C,38,9,2) OP(C,39,9,3) \
    OP(C,40,10,0) OP(C,41,10,1) OP(C,42,10,2) OP(C,43,10,3) OP(C,44,11,0) OP(C,45,11,1) OP(C,46,11,2) OP(C,47,11,3) \
    OP(C,48,12,0) OP(C,49,12,1) OP(C,50,12,2) OP(C,51,12,3) OP(C,52,13,0) OP(C,53,13,1) OP(C,54,13,2) OP(C,55,13,3) \
    OP(C,56,14,0) OP(C,57,14,1) OP(C,58,14,2) OP(C,59,14,3) OP(C,60,15,0) OP(C,61,15,1) OP(C,62,15,2) OP(C,63,15,3)
// 16 (Q, 4Q, 4Q+1, 4Q+2, 4Q+3) groups
#define REPW(OP) OP(0,0,1,2,3) OP(1,4,5,6,7) OP(2,8,9,10,11) OP(3,12,13,14,15) OP(4,16,17,18,19) \
    OP(5,20,21,22,23) OP(6,24,25,26,27) OP(7,28,29,30,31) OP(8,32,33,34,35) OP(9,36,37,38,39) \
    OP(10,40,41,42,43) OP(11,44,45,46,47) OP(12,48,49,50,51) OP(13,52,53,54,55) OP(14,56,57,58,59) \
    OP(15,60,61,62,63)
#define REP16C(OP, C) OP(C,0) OP(C,1) OP(C,2) OP(C,3) OP(C,4) OP(C,5) OP(C,6) OP(C,7) \
    OP(C,8) OP(C,9) OP(C,10) OP(C,11) OP(C,12) OP(C,13) OP(C,14) OP(C,15)

// ---------------------------------------------------------------------------
// 1) x[b][t][d] (f32) -> Xt[d][b*Tn+t] (bf16), LDS 64x64 tile transpose.
// ---------------------------------------------------------------------------
__global__ __launch_bounds__(256) void k_transpose(const float* __restrict__ x,
                                                   u16* __restrict__ Xt) {
    int tt = blockIdx.x;   // t-tile 0..31
    int dt = blockIdx.y;   // d-tile 0..7
    int b  = blockIdx.z;   // 0..31
    __shared__ u16 sT[64][68];  // [d][t], padded
    int tid = threadIdx.x;
    int row = tid >> 4;            // 0..15 (t)
    int c4  = (tid & 15) * 4;      // 0..60 (d)
    const float* src = x + ((long)b * Tn + (long)tt * 64) * Dn + dt * 64;
#pragma unroll
    for (int q = 0; q < 4; q++) {
        int r = row + q * 16;
        floatx4 v = *(const floatx4*)(src + (long)r * Dn + c4);
        sT[c4 + 0][r] = f2bf(v[0]);
        sT[c4 + 1][r] = f2bf(v[1]);
        sT[c4 + 2][r] = f2bf(v[2]);
        sT[c4 + 3][r] = f2bf(v[3]);
    }
    __syncthreads();
    int drow = tid >> 3;           // 0..31 (d)
    int koff = (tid & 7) * 8;      // 0..56 (t)
    long kout = (long)b * Tn + (long)tt * 64 + koff;
#pragma unroll
    for (int p = 0; p < 2; p++) {
        int dr = drow + p * 32;
        u16 tmp[8];
#pragma unroll
        for (int j = 0; j < 8; j++) tmp[j] = sT[dr][koff + j];
        *(short8*)(Xt + (long)(dt * 64 + dr) * BT + kout) = *(short8*)tmp;
    }
}

// ---------------------------------------------------------------------------
// 2) mu[b][d] = (1/T) sum_t Xt[d][b*Tn+t]   (wave per (b,d))
// ---------------------------------------------------------------------------
__global__ __launch_bounds__(256) void k_mu(const u16* __restrict__ Xt,
                                            float* __restrict__ mu) {
    int tid = threadIdx.x;
    int wave = tid >> 6, lane = tid & 63;
    int p = blockIdx.x * 4 + wave;      // 0..16383 == b*512+d
    int b = p >> 9, d = p & 511;
    const u16* src = Xt + (long)d * BT + (long)b * Tn;
    float s = 0.f;
#pragma unroll
    for (int c = 0; c < 4; c++) {
        short8 v = *(const short8*)(src + c * 512 + lane * 8);
#pragma unroll
        for (int j = 0; j < 8; j++) s += bf2f((u16)v[j]);
    }
#pragma unroll
    for (int off = 32; off; off >>= 1) s += __shfl_down(s, off, 64);
    if (lane == 0) mu[p] = s * (1.0f / Tn);
}

// ---------------------------------------------------------------------------
// 3) Gram partials: partial[chunk][d][e] = sum_{k in chunk} Xt[d][k]*Xt[e][k]
//    bf16 MFMA 16x16x32, 128x128 tile, BK=32, 16 K-chunks x 10 sym positions.
// ---------------------------------------------------------------------------
#define LDK 40   // padded LDS row stride (bf16 elems) to spread banks
__global__ __launch_bounds__(256) void k_gram(const u16* __restrict__ Xt,
                                              float* __restrict__ partial) {
    int chunk = blockIdx.x;             // 0..15 (K-chunk of 4096)
    int pos = blockIdx.y;               // 0..9 upper-block-triangle positions
    int di = (pos < 4) ? 0 : (pos < 7) ? 1 : (pos < 9) ? 2 : 3;
    int start = di * 4 - (di * (di - 1)) / 2;   // 0,4,7,9
    int ei = di + (pos - start);
    int d0 = di * 128, e0 = ei * 128;

    __shared__ u16 sA[128 * LDK];
    __shared__ u16 sB[128 * LDK];
    int tid = threadIdx.x;
    int wave = tid >> 6, lane = tid & 63;
    int wm = wave & 1, wn = wave >> 1;  // 2x2 waves over 128x128
    int lrow = tid >> 2;                // 0..63
    int lk = (tid & 3) * 8;             // 0,8,16,24
    const u16* gA = Xt + (long)(d0 + lrow) * BT + (long)chunk * 4096 + lk;
    const u16* gB = Xt + (long)(e0 + lrow) * BT + (long)chunk * 4096 + lk;
    int m = lane & 15, g = lane >> 4;

    floatx4 acc[4][4] = {};
    for (int kk = 0; kk < 4096; kk += 32) {
        short8 a0 = *(const short8*)(gA + kk);
        short8 a1 = *(const short8*)(gA + 64l * BT + kk);
        short8 b0 = *(const short8*)(gB + kk);
        short8 b1 = *(const short8*)(gB + 64l * BT + kk);
        __syncthreads();   // previous iteration's LDS reads done
        *(short8*)(sA + lrow * LDK + lk) = a0;
        *(short8*)(sA + (lrow + 64) * LDK + lk) = a1;
        *(short8*)(sB + lrow * LDK + lk) = b0;
        *(short8*)(sB + (lrow + 64) * LDK + lk) = b1;
        __syncthreads();
        short8 af[4], bf[4];
#pragma unroll
        for (int i = 0; i < 4; i++)
            af[i] = *(const short8*)(sA + (wm * 64 + i * 16 + m) * LDK + g * 8);
#pragma unroll
        for (int j = 0; j < 4; j++)
            bf[j] = *(const short8*)(sB + (wn * 64 + j * 16 + m) * LDK + g * 8);
#pragma unroll
        for (int i = 0; i < 4; i++)
#pragma unroll
            for (int j = 0; j < 4; j++)
                acc[i][j] = __builtin_amdgcn_mfma_f32_16x16x32_bf16(af[i], bf[j], acc[i][j], 0, 0, 0);
    }
    // C/D layout: col = lane&15, row = (lane>>4)*4 + reg   [m89-verified]
    float* P = partial + (long)chunk * (512l * 512);
    int col = lane & 15, rowg = (lane >> 4) * 4;
#pragma unroll
    for (int i = 0; i < 4; i++)
#pragma unroll
        for (int j = 0; j < 4; j++) {
            int rr = d0 + wm * 64 + i * 16 + rowg;
            int cc = e0 + wn * 64 + j * 16 + col;
#pragma unroll
            for (int r = 0; r < 4; r++) P[(long)(rr + r) * 512 + cc] = acc[i][j][r];
        }
}

// ---------------------------------------------------------------------------
// 4) cov[d][e] = (G[d][e] - T * sum_b mu[b,d]*mu[b,e]) / ((T-1)*B)
// ---------------------------------------------------------------------------
__global__ __launch_bounds__(256) void k_assemble(const float* __restrict__ partial,
                                                  const float* __restrict__ mu,
                                                  float* __restrict__ A) {
    int d = blockIdx.y;
    int e = blockIdx.x * 256 + threadIdx.x;
    int bd = d >> 7, be = e >> 7;
    long idx = (bd <= be) ? ((long)d * 512 + e) : ((long)e * 512 + d);  // symmetric mirror
    float s = 0.f;
#pragma unroll
    for (int c = 0; c < 16; c++) s += partial[c * (512l * 512) + idx];
    float msum = 0.f;
#pragma unroll
    for (int b = 0; b < 32; b++) msum += mu[b * 512 + d] * mu[b * 512 + e];
    A[(long)d * 512 + e] = (s - (float)Tn * msum) * (1.0f / ((Tn - 1.0f) * Bn));
}

// ---------------------------------------------------------------------------
// 5a) Fused Cholesky panel, 64 threads (1 wave), nb+1 blocks.
//     Every block factors the 64x64 diag in NAMED registers with BATCHED
//     shuffles (all shfl of a step issued into temps before any fma -> one
//     wait per step, not per element; round-6's 40us/launch was wait-per-use
//     bpermute serialization). Block 0 writes the diag back. Blocks 1..nb:
//     store L11 to LDS (stride 68 -> rows 16B-aligned), then solve one
//     64-row stripe with BATCHED uniform ds_read_b128 L-row loads per step.
// ---------------------------------------------------------------------------
__global__ __launch_bounds__(64, 1) void k_chol_panel(float* __restrict__ A, int kb) {
    const int k0 = kb * 64;
    const int lane = threadIdx.x;
    __shared__ float sD[64 * 68];
    __shared__ float sInv[64];
    const floatx4 z4 = {0.f, 0.f, 0.f, 0.f};

    // ---- load own diag row into named regs (16 dwordx4, L2-hot) ----
    const float* Dr = A + (long)(k0 + lane) * 512 + k0;
#define LDV(Q,A0,A1,A2,A3) floatx4 v##Q = *(const floatx4*)(Dr + 4*(Q));
    REPW(LDV)
#undef LDV
#define DECR(C,M,Mq,e) float r##M = v##Mq[(e)];
    REPQ(DECR, 0)
#undef DECR

    // ---- factor: 64 steps, shuffle batch then fma batch ----
    float vinv = 0.f;
#define SH1(K,J) float t##J = ((J) > (K)) ? __shfl(lik, (J), 64) : 0.0f;
#define FM1(K,J) if ((J) > (K)) r##J = fmaf(-lik, t##J, r##J);
#define STEP(K) { float akk = __shfl(r##K, (K), 64); float sd = sqrtf(akk); \
                  float inv = 1.0f / sd; float lik = (lane == (K)) ? sd : r##K * inv; \
                  r##K = lik; if (lane == (K)) vinv = inv; REPJ(SH1, K) REPJ(FM1, K) }
    REP64(STEP)
#undef STEP
#undef FM1
#undef SH1

    if (blockIdx.x == 0) {
        // write back factored diag (junk upper triangle never read downstream)
        float* W = A + (long)(k0 + lane) * 512 + k0;
#define STW(Q,A0,A1,A2,A3) { floatx4 w; w[0]=r##A0; w[1]=r##A1; w[2]=r##A2; w[3]=r##A3; \
                             *(floatx4*)(W + 4*(Q)) = w; }
        REPW(STW)
#undef STW
        return;
    }

    // ---- stash L11 (row lane) + inv in LDS for uniform broadcast reads ----
#define STD(Q,A0,A1,A2,A3) { floatx4 w; w[0]=r##A0; w[1]=r##A1; w[2]=r##A2; w[3]=r##A3; \
                             *(floatx4*)(sD + lane * 68 + 4*(Q)) = w; }
    REPW(STD)
#undef STD
    sInv[lane] = vinv;
    __syncthreads();

    // ---- TRSM: lane = row of this block's 64-row stripe ----
    int rbase = k0 + 64 + (blockIdx.x - 1) * 64;
    const float* R = A + (long)(rbase + lane) * 512 + k0;
#define LDA(Q,A0,A1,A2,A3) floatx4 u##Q = *(const floatx4*)(R + 4*(Q));
    REPW(LDA)
#undef LDA
#define DECA(C,M,Mq,e) float a##M = u##Mq[(e)];
    REPQ(DECA, 0)
#undef DECA
    // per step C: 16 batched uniform b128 reads of L-row C, then guarded fmas
#define LQ(C,Q) floatx4 q##Q = ((C) > 4*(Q)) ? *(const floatx4*)(sD + (C) * 68 + 4*(Q)) : z4;
#define TF(C,M,Mq,e) if ((M) < (C)) acc##e = fmaf(a##M, q##Mq[(e)], acc##e);
#define TSTEP(C) { REP16C(LQ, C) float acc0 = 0.f, acc1 = 0.f, acc2 = 0.f, acc3 = 0.f; \
                   REPQ(TF, C) a##C = (a##C - ((acc0 + acc1) + (acc2 + acc3))) * sInv[(C)]; }
    REP64(TSTEP)
#undef TSTEP
#undef TF
#undef LQ

    float* Wr = A + (long)(rbase + lane) * 512 + k0;
#define STA(Q,A0,A1,A2,A3) { floatx4 w; w[0]=a##A0; w[1]=a##A1; w[2]=a##A2; w[3]=a##A3; \
                             *(floatx4*)(Wr + 4*(Q)) = w; }
    REPW(STA)
#undef STA
}

// ---------------------------------------------------------------------------
// 5b) Trailing update: A22 -= L21 * L21^T, one 64x64 tile per block (fp32).
// ---------------------------------------------------------------------------
__global__ __launch_bounds__(256) void k_chol_update(float* __restrict__ A, int kb) {
    int k0 = kb * 64, base = k0 + 64;
    int idx = blockIdx.x, ti = 0;
    while (idx > ti) { idx -= ti + 1; ti++; }
    int tj = idx;
    int r0 = base + ti * 64, c0 = base + tj * 64;
    __shared__ float sI[64][65];
    __shared__ float sJ[64][65];
    int tid = threadIdx.x;
    int row = tid >> 4, c4 = (tid & 15) * 4;
#pragma unroll
    for (int q = 0; q < 4; q++) {
        int rr = row + q * 16;
        *(floatx4*)&sI[rr][c4] = *(const floatx4*)(A + (long)(r0 + rr) * 512 + k0 + c4);
        *(floatx4*)&sJ[rr][c4] = *(const floatx4*)(A + (long)(c0 + rr) * 512 + k0 + c4);
    }
    __syncthreads();
    int ri = (tid >> 4) * 4, cj = (tid & 15) * 4;
    float acc[4][4] = {};
    for (int k = 0; k < 64; k += 4) {
        floatx4 av[4], bv[4];
#pragma unroll
        for (int ii = 0; ii < 4; ii++) av[ii] = *(const floatx4*)&sI[ri + ii][k];
#pragma unroll
        for (int jj = 0; jj < 4; jj++) bv[jj] = *(const floatx4*)&sJ[cj + jj][k];
#pragma unroll
        for (int ii = 0; ii < 4; ii++)
#pragma unroll
            for (int jj = 0; jj < 4; jj++)
#pragma unroll
                for (int q = 0; q < 4; q++)
                    acc[ii][jj] = fmaf(av[ii][q], bv[jj][q], acc[ii][jj]);
    }
#pragma unroll
    for (int ii = 0; ii < 4; ii++) {
        float* dst = A + (long)(r0 + ri + ii) * 512 + c0 + cj;
        floatx4 old = *(const floatx4*)dst;
#pragma unroll
        for (int jj = 0; jj < 4; jj++) old[jj] -= acc[ii][jj];
        *(floatx4*)dst = old;
    }
}

// ---------------------------------------------------------------------------
// 6) out[i][d] = mean[d] + sum_{e<=d} z[i][e] * L[d][e]
// ---------------------------------------------------------------------------
__global__ __launch_bounds__(512) void k_output(const float* __restrict__ z,
                                                const float* __restrict__ A,
                                                const float* __restrict__ mu,
                                                float* __restrict__ out) {
    int i = blockIdx.x, d = threadIdx.x;
    __shared__ float sz[512];
    sz[d] = z[(long)i * 512 + d];
    __syncthreads();
    float mean = 0.f;
#pragma unroll
    for (int b = 0; b < 32; b++) mean += mu[b * 512 + d];
    mean *= (1.0f / 32.0f);
    const float* Lr = A + (long)d * 512;
    float acc = 0.f;
    int dmax = d + 1;
    int e4 = dmax & ~3;
    for (int e = 0; e < e4; e += 4) {
        floatx4 l = *(const floatx4*)(Lr + e);
        acc += l[0] * sz[e] + l[1] * sz[e + 1] + l[2] * sz[e + 2] + l[3] * sz[e + 3];
    }
    for (int e = e4; e < dmax; e++) acc += Lr[e] * sz[e];
    out[(long)i * 512 + d] = mean + acc;
}

// ---------------------------------------------------------------------------
extern "C" void kernel_launch(void* const* d_in, const int* in_sizes, int n_in,
                              void* d_out, int out_size, void* d_ws, size_t ws_size,
                              hipStream_t stream) {
    const float* x = (const float*)d_in[0];
    const float* z = (const float*)d_in[1];
    float* out = (float*)d_out;
    char* ws = (char*)d_ws;
    // ws layout: Xt 67108864B | mu 65536B | partial 16777216B | A 1048576B
    u16* Xt = (u16*)ws;
    float* mu = (float*)(ws + 67108864);
    float* partial = (float*)(ws + 67108864 + 65536);
    float* A = (float*)(ws + 67108864 + 65536 + 16777216);

    k_transpose<<<dim3(32, 8, 32), 256, 0, stream>>>(x, Xt);
    k_mu<<<4096, 256, 0, stream>>>(Xt, mu);
    k_gram<<<dim3(16, 10), 256, 0, stream>>>(Xt, partial);
    k_assemble<<<dim3(2, 512), 256, 0, stream>>>(partial, mu, A);
    for (int kb = 0; kb < 8; kb++) {
        int nb = 7 - kb;                 // 64-row stripes below the diagonal
        k_chol_panel<<<nb + 1, 64, 0, stream>>>(A, kb);
        int tiles = nb * (nb + 1) / 2;
        if (tiles > 0) k_chol_update<<<tiles, 256, 0, stream>>>(A, kb);
    }
    k_output<<<32, 512, 0, stream>>>(z, A, mu, out);
}